// Round 10
// baseline (307.326 us; speedup 1.0000x reference)
//
#include <hip/hip_runtime.h>

#define BB 4
#define NT 256
#define NZ 384
#define NX 384
#define NREC 128
#define NZX (NZ*NX)        // 147456
#define BNZX (BB*NZX)      // 589824
#define DT 0.001f
#define INV_DH2 0.01f      // 1/(10*10)

#define TR 24              // owned tile rows
#define TC 48              // owned tile cols
#define HALO 8
#define RR 40              // region rows = 8 waves x 5
#define RC 64              // region cols = 64 lanes
#define NTDR 16            // 384/24
#define NTDC 8             // 384/48
#define NBLK 512           // 4 batches x 128 tiles -> exactly 2 blocks/CU
#define NTHR 512           // 8 waves: wave w owns rows 5w..5w+4, lane = col
#define FSTRIDE 16         // flag spread (64 B)
#define DYN_LDS 40960      // pad LDS to ~54.3KB: HW caps residency at 2/CU,
                           // 512 blocks / 256 CUs -> EXACTLY 2 each (pigeonhole)

__global__ void wave_init(unsigned* flags) {
    int i = blockIdx.x * blockDim.x + threadIdx.x;
    if (i < NBLK * FSTRIDE) flags[i] = 0u;
}

__device__ inline float dpp_shl1(float v) {
    return __int_as_float(__builtin_amdgcn_update_dpp(
        0, __float_as_int(v), 0x130 /*WAVE_SHL1*/, 0xf, 0xf, true));
}
__device__ inline float dpp_shr1(float v) {
    return __int_as_float(__builtin_amdgcn_update_dpp(
        0, __float_as_int(v), 0x138 /*WAVE_SHR1*/, 0xf, 0xf, true));
}

__global__ __launch_bounds__(NTHR)
void wave_tiled(float* __restrict__ ws, const float* __restrict__ vp,
                const float* __restrict__ x,
                const int* __restrict__ src_y, const int* __restrict__ src_x,
                const int* __restrict__ rec_y, const int* __restrict__ rec_x,
                float* __restrict__ y) {
    __shared__ float bnd[2][16][RC];     // [parity][2*wave+{top,bot}][col]
    __shared__ float recBuf[NREC][8];    // receiver samples, flushed per window
    __shared__ float xs[NT];             // this batch's source trace
    __shared__ int recLoc[NREC], recOut[NREC];
    __shared__ int recCnt;

    unsigned* flags = (unsigned*)(ws + 4*BNZX);

    const int tid = threadIdx.x;
    const int col = tid & 63;
    const int w   = tid >> 6;
    const int r0w = w * 5;
    const int blk = blockIdx.x;
    const int b   = blk >> 7;            // 0..3
    const int rem = blk & 127;
    const int tz  = rem >> 3;            // 0..15
    const int tx  = rem & 7;             // 0..7
    const int oz  = tz*TR - HALO, ox = tx*TC - HALO;
    const int gx  = ox + col;
    const int sy = src_y[b], sx = src_x[b];

    if (tid == 0) recCnt = 0;
    for (int k = tid; k < 2*16*RC; k += NTHR) ((float*)bnd)[k] = 0.f;
    for (int k = tid; k < NT; k += NTHR) xs[k] = x[b*NT + k];
    __syncthreads();
    for (int r = tid; r < NREC; r += NTHR) {
        int ry = rec_y[r], rx = rec_x[r];
        if (ry/TR == tz && rx/TC == tx) {
            int p = atomicAdd(&recCnt, 1);
            recLoc[p] = ((ry - oz) << 6) | (rx - ox);
            recOut[p] = b*NREC + r;
        }
    }
    __syncthreads();

    // per-thread receiver ownership cache (cap 4, LDS-loop fallback)
    int myN = 0, myM[4], myP[4];
    bool ovf = false;
    for (int p = 0; p < recCnt; ++p) {
        int rl = recLoc[p];
        if ((rl & 63) == col) {
            int rm = (rl >> 6) - r0w;
            if ((unsigned)rm < 5u) {
                if (myN < 4) { myM[myN] = rm; myP[myN] = p; ++myN; }
                else ovf = true;
            }
        }
    }
    // wave-uniform: does ANY lane of this wave own a receiver? (~1 of 8 waves
    // does; the 48-instr/step sampling block was ~44% of all VALU issue)
    const bool wRec = __any(myN > 0);

    // neighbor ids for the sync (lanes 0..7 of wave 0; others self)
    int nbId = blk;
    if (tid < 8) {
        int d = tid + (tid >= 4);            // 0..8 skipping center 4
        int nz2 = tz + d/3 - 1, nx2 = tx + d%3 - 1;
        if ((unsigned)nz2 < (unsigned)NTDR && (unsigned)nx2 < (unsigned)NTDC)
            nbId = (b << 7) | (nz2 << 3) | nx2;
    }

    // per-thread column state: 5 rows in registers
    float cur[5], prv[5], c2i[5];
    #pragma unroll
    for (int m = 0; m < 5; ++m) {
        cur[m] = 0.f; prv[m] = 0.f;
        const int gz = oz + r0w + m;
        const bool inner = (gz > 0 && gz < NZ-1 && gx > 0 && gx < NX-1);
        const float v = inner ? vp[gz*NX + gx] * DT : 0.f;
        c2i[m] = v * v * INV_DH2;    // 0 at edges -> lap auto-masked
    }
    const bool srcCol = (gx == sx);
    const int  srcM   = sy - oz - r0w;
    const int  iuUp   = (2*w-1 < 0) ? 0 : 2*w-1;
    const int  iuDn   = (2*w+2 > 15) ? 15 : 2*w+2;
    // light-cone: rows needed at window-step k=(t&7)+1 are [k, RR-k).
    // Waves 0/7 hold pure-halo rows (0-4 / 35-39), dead for k>=5 and fully
    // reloaded at the exchange -> they skip stencil+bnd for (t&7)>=4.
    // (Their rows store no ring cells, own no receivers, and the stale bnd
    // values they'd provide only feed other provably-dead cells.)
    const bool edgeW = (w == 0) || (w == 7);
    __syncthreads();

    #pragma unroll 1
    for (int t = 0; t < NT; ++t) {
        const bool act = !(edgeW && (t & 7) >= 4);
        if (act) {
            const int pr = t & 1, pw = pr ^ 1;
            const float upB = bnd[pr][iuUp][col];
            const float dnB = bnd[pr][iuDn][col];

            float hn[5];
            #pragma unroll
            for (int m = 0; m < 5; ++m) {
                const float ce = cur[m];
                const float up = (m == 0) ? upB : cur[m-1];
                const float dn = (m == 4) ? dnB : cur[m+1];
                const float lf = dpp_shl1(ce);
                const float rt = dpp_shr1(ce);
                const float s  = (up + dn) + (lf + rt);
                hn[m] = fmaf(2.f, ce, -prv[m]) + c2i[m] * fmaf(-4.f, ce, s);
            }
            #pragma unroll
            for (int m = 0; m < 5; ++m) { prv[m] = cur[m]; cur[m] = hn[m]; }

            if (srcCol && (unsigned)srcM < 5u) {
                const float xv = xs[t];
                #pragma unroll
                for (int m = 0; m < 5; ++m) if (m == srcM) cur[m] += xv;
            }
            // receiver sampling -> LDS buffer (wave-gated)
            if (wRec) {
                const int s2 = t & 7;
                if (ovf) {
                    for (int p = 0; p < recCnt; ++p) {
                        int rl = recLoc[p];
                        if ((rl & 63) == col) {
                            int rm = (rl >> 6) - r0w;
                            if ((unsigned)rm < 5u) {
                                float v = cur[0];
                                #pragma unroll
                                for (int m = 1; m < 5; ++m) if (rm == m) v = cur[m];
                                recBuf[p][s2] = v;
                            }
                        }
                    }
                } else {
                    #pragma unroll
                    for (int k = 0; k < 4; ++k) {
                        if (k < myN) {
                            float v = cur[0];
                            #pragma unroll
                            for (int m = 1; m < 5; ++m) if (myM[k] == m) v = cur[m];
                            recBuf[myP[k]][s2] = v;
                        }
                    }
                }
            }
            bnd[pw][2*w  ][col] = cur[0];
            bnd[pw][2*w+1][col] = cur[4];
        }

        if ((t & 7) == 7) {
            const int o = t >> 3;
            const bool exch = (t < NT-1);
            const int pw2 = (t & 1) ^ 1;
            float* Gc = ws + (size_t)(o & 1) * 2*BNZX;   // ping-pong frames
            float* Gp = Gc + BNZX;
            if (exch) {
                // ring: depth [HALO,2*HALO) band of the owned region
                #pragma unroll
                for (int m = 0; m < 5; ++m) {
                    const int i = r0w + m;
                    const bool ring =
                        (i >= HALO && i < RR-HALO && col >= HALO && col < RC-HALO)
                     && !(i >= 2*HALO && i < RR-2*HALO &&
                          col >= 2*HALO && col < RC-2*HALO);
                    if (ring) {   // ring cells always in-domain
                        const size_t g = (size_t)b*NZX + (size_t)(oz+i)*NX + gx;
                        __hip_atomic_store(&Gc[g], cur[m],
                                           __ATOMIC_RELAXED, __HIP_MEMORY_SCOPE_AGENT);
                        __hip_atomic_store(&Gp[g], prv[m],
                                           __ATOMIC_RELAXED, __HIP_MEMORY_SCOPE_AGENT);
                    }
                }
            }
            __syncthreads();   // recBuf visible; ring stores drained (vmcnt0)
            if (exch && tid == 0)
                __hip_atomic_store(&flags[blk * FSTRIDE], (unsigned)(o + 1),
                                   __ATOMIC_RELAXED, __HIP_MEMORY_SCOPE_AGENT);
            // receiver flush overlaps the neighbor wait
            for (int k = tid; k < recCnt*8; k += NTHR) {
                int p = k >> 3, s2 = k & 7;
                y[(size_t)((o<<3)+s2)*(BB*NREC) + recOut[p]] = recBuf[p][s2];
            }
            if (exch) {
                const unsigned gen = (unsigned)(o + 1);
                if (tid < 64) {
                    for (;;) {
                        unsigned f = __hip_atomic_load(&flags[nbId * FSTRIDE],
                                         __ATOMIC_RELAXED, __HIP_MEMORY_SCOPE_AGENT);
                        if (__all(f >= gen)) break;
                        __builtin_amdgcn_s_sleep(1);
                    }
                }
                __syncthreads();
                const bool colH = (col < HALO || col >= RC-HALO);
                const bool gxIn = (gx >= 0 && gx < NX);
                #pragma unroll
                for (int m = 0; m < 5; ++m) {
                    const int i = r0w + m;
                    if (colH || i < HALO || i >= RR-HALO) {
                        const int gz = oz + i;
                        if (gxIn && gz >= 0 && gz < NZ) {   // BOTH bounds (r2 lesson)
                            const size_t g = (size_t)b*NZX + (size_t)gz*NX + gx;
                            cur[m] = __hip_atomic_load(&Gc[g],
                                         __ATOMIC_RELAXED, __HIP_MEMORY_SCOPE_AGENT);
                            prv[m] = __hip_atomic_load(&Gp[g],
                                         __ATOMIC_RELAXED, __HIP_MEMORY_SCOPE_AGENT);
                        } else { cur[m] = 0.f; prv[m] = 0.f; }
                    }
                }
                // refresh bnd (essential for edge waves whose step-loop bnd
                // writes were skipped: wave1/wave6 read these next step)
                bnd[pw2][2*w  ][col] = cur[0];
                bnd[pw2][2*w+1][col] = cur[4];
            }
        }
        __syncthreads();
    }
}

extern "C" void kernel_launch(void* const* d_in, const int* in_sizes, int n_in,
                              void* d_out, int out_size, void* d_ws, size_t ws_size,
                              hipStream_t stream) {
    const float* x     = (const float*)d_in[0];
    const float* vp    = (const float*)d_in[1];
    const int*   src_y = (const int*)d_in[2];
    const int*   src_x = (const int*)d_in[3];
    const int*   rec_y = (const int*)d_in[4];
    const int*   rec_x = (const int*)d_in[5];
    float* y  = (float*)d_out;
    float* ws = (float*)d_ws;   // 4*BNZX frame floats + 512*16 flag words

    wave_init<<<(NBLK*FSTRIDE + 255)/256, 256, 0, stream>>>((unsigned*)(ws + 4*BNZX));
    // DYN_LDS bytes of (unused) dynamic LDS pad the group segment to ~54.3KB:
    // hardware can then host at most 2 blocks/CU -> exactly 2 everywhere.
    wave_tiled<<<NBLK, NTHR, DYN_LDS, stream>>>(ws, vp, x, src_y, src_x,
                                                rec_y, rec_x, y);
}

// Round 11
// 272.273 us; speedup vs baseline: 1.1287x; 1.1287x over previous
//
#include <hip/hip_runtime.h>

#define BB 4
#define NT 256
#define NZ 384
#define NX 384
#define NREC 128
#define NZX (NZ*NX)        // 147456
#define BNZX (BB*NZX)      // 589824
#define DT 0.001f
#define INV_DH2 0.01f      // 1/(10*10)

#define TR 24              // owned tile rows
#define TC 48              // owned tile cols
#define HALO 8
#define RR 40              // region rows = 8 waves x 5
#define RC 64              // region cols = 64 lanes
#define NTDR 16            // 384/24
#define NTDC 8             // 384/48
#define NBLK 512           // 4 batches x 128 tiles -> exactly 2 blocks/CU
#define NTHR 512           // 8 waves: wave w owns rows 5w..5w+4, lane = col
#define FSTRIDE 16         // flag spread (64 B)
#define DYN_LDS 40960      // pad LDS to ~54.3KB: HW caps residency at 2/CU,
                           // 512 blocks / 256 CUs -> EXACTLY 2 each (pigeonhole)

__global__ void wave_init(unsigned* flags) {
    int i = blockIdx.x * blockDim.x + threadIdx.x;
    if (i < NBLK * FSTRIDE) flags[i] = 0u;
}

__device__ inline float dpp_shl1(float v) {
    return __int_as_float(__builtin_amdgcn_update_dpp(
        0, __float_as_int(v), 0x130 /*WAVE_SHL1*/, 0xf, 0xf, true));
}
__device__ inline float dpp_shr1(float v) {
    return __int_as_float(__builtin_amdgcn_update_dpp(
        0, __float_as_int(v), 0x138 /*WAVE_SHR1*/, 0xf, 0xf, true));
}

__global__ __launch_bounds__(NTHR)
void wave_tiled(float* __restrict__ ws, const float* __restrict__ vp,
                const float* __restrict__ x,
                const int* __restrict__ src_y, const int* __restrict__ src_x,
                const int* __restrict__ rec_y, const int* __restrict__ rec_x,
                float* __restrict__ y) {
    __shared__ float bnd[2][16][RC];     // [parity][2*wave+{top,bot}][col]
    __shared__ float recBuf[NREC][8];    // receiver samples, flushed per window
    __shared__ float xs[NT];             // this batch's source trace
    __shared__ int recLoc[NREC], recOut[NREC];
    __shared__ int recCnt;

    unsigned* flags = (unsigned*)(ws + 4*BNZX);

    const int tid = threadIdx.x;
    const int col = tid & 63;
    const int w   = tid >> 6;
    const int r0w = w * 5;
    const int blk = blockIdx.x;
    const int b   = blk >> 7;            // 0..3
    const int rem = blk & 127;
    const int tz  = rem >> 3;            // 0..15
    const int tx  = rem & 7;             // 0..7
    const int oz  = tz*TR - HALO, ox = tx*TC - HALO;
    const int gx  = ox + col;
    const int sy = src_y[b], sx = src_x[b];

    if (tid == 0) recCnt = 0;
    for (int k = tid; k < 2*16*RC; k += NTHR) ((float*)bnd)[k] = 0.f;
    for (int k = tid; k < NT; k += NTHR) xs[k] = x[b*NT + k];
    __syncthreads();
    for (int r = tid; r < NREC; r += NTHR) {
        int ry = rec_y[r], rx = rec_x[r];
        if (ry/TR == tz && rx/TC == tx) {
            int p = atomicAdd(&recCnt, 1);
            recLoc[p] = ((ry - oz) << 6) | (rx - ox);
            recOut[p] = b*NREC + r;
        }
    }
    __syncthreads();

    // per-thread receiver ownership cache (cap 4, LDS-loop fallback)
    int myN = 0, myM[4], myP[4];
    bool ovf = false;
    for (int p = 0; p < recCnt; ++p) {
        int rl = recLoc[p];
        if ((rl & 63) == col) {
            int rm = (rl >> 6) - r0w;
            if ((unsigned)rm < 5u) {
                if (myN < 4) { myM[myN] = rm; myP[myN] = p; ++myN; }
                else ovf = true;
            }
        }
    }

    // neighbor ids for the sync (lanes 0..7 of wave 0; others self)
    int nbId = blk;
    if (tid < 8) {
        int d = tid + (tid >= 4);            // 0..8 skipping center 4
        int nz2 = tz + d/3 - 1, nx2 = tx + d%3 - 1;
        if ((unsigned)nz2 < (unsigned)NTDR && (unsigned)nx2 < (unsigned)NTDC)
            nbId = (b << 7) | (nz2 << 3) | nx2;
    }

    // per-thread column state: 5 rows in registers
    float cur[5], prv[5], c2i[5];
    #pragma unroll
    for (int m = 0; m < 5; ++m) {
        cur[m] = 0.f; prv[m] = 0.f;
        const int gz = oz + r0w + m;
        const bool inner = (gz > 0 && gz < NZ-1 && gx > 0 && gx < NX-1);
        const float v = inner ? vp[gz*NX + gx] * DT : 0.f;
        c2i[m] = v * v * INV_DH2;    // 0 at edges -> lap auto-masked
    }
    const bool srcCol = (gx == sx);
    const int  srcM   = sy - oz - r0w;
    const int  iuUp   = (2*w-1 < 0) ? 0 : 2*w-1;
    const int  iuDn   = (2*w+2 > 15) ? 15 : 2*w+2;
    __syncthreads();

    #pragma unroll 1
    for (int t = 0; t < NT; ++t) {
        const int pr = t & 1, pw = pr ^ 1;
        const float upB = bnd[pr][iuUp][col];
        const float dnB = bnd[pr][iuDn][col];

        float hn[5];
        #pragma unroll
        for (int m = 0; m < 5; ++m) {
            const float ce = cur[m];
            const float up = (m == 0) ? upB : cur[m-1];
            const float dn = (m == 4) ? dnB : cur[m+1];
            const float lf = dpp_shl1(ce);
            const float rt = dpp_shr1(ce);
            const float s  = (up + dn) + (lf + rt);
            hn[m] = fmaf(2.f, ce, -prv[m]) + c2i[m] * fmaf(-4.f, ce, s);
        }
        #pragma unroll
        for (int m = 0; m < 5; ++m) { prv[m] = cur[m]; cur[m] = hn[m]; }

        if (srcCol && (unsigned)srcM < 5u) {
            const float xv = xs[t];
            #pragma unroll
            for (int m = 0; m < 5; ++m) if (m == srcM) cur[m] += xv;
        }
        // receiver sampling -> LDS buffer (no global ops in the step loop)
        {
            const int s2 = t & 7;
            if (ovf) {
                for (int p = 0; p < recCnt; ++p) {
                    int rl = recLoc[p];
                    if ((rl & 63) == col) {
                        int rm = (rl >> 6) - r0w;
                        if ((unsigned)rm < 5u) {
                            float v = cur[0];
                            #pragma unroll
                            for (int m = 1; m < 5; ++m) if (rm == m) v = cur[m];
                            recBuf[p][s2] = v;
                        }
                    }
                }
            } else {
                #pragma unroll
                for (int k = 0; k < 4; ++k) {
                    if (k < myN) {
                        float v = cur[0];
                        #pragma unroll
                        for (int m = 1; m < 5; ++m) if (myM[k] == m) v = cur[m];
                        recBuf[myP[k]][s2] = v;
                    }
                }
            }
        }
        bnd[pw][2*w  ][col] = cur[0];
        bnd[pw][2*w+1][col] = cur[4];

        // Early prv-frame ring store: after step s=6 of a window, cur equals
        // the window-end prv. Issuing the prv-half here lets its sc1 drain
        // overlap step 7's compute instead of sitting in the pre-flag
        // vmcnt(0) drain. Same values, same frame, one step earlier.
        // Ping-pong safety: reaching window o step 6 requires sync gen o,
        // which implies neighbors finished reading this parity frame at the
        // end of window o-2 (r0's 2-deep argument, +1 step of margin).
        if ((t & 7) == 6 && t < NT-2) {
            const int o = t >> 3;
            float* Gp = ws + (size_t)(o & 1) * 2*BNZX + BNZX;
            #pragma unroll
            for (int m = 0; m < 5; ++m) {
                const int i = r0w + m;
                const bool ring =
                    (i >= HALO && i < RR-HALO && col >= HALO && col < RC-HALO)
                 && !(i >= 2*HALO && i < RR-2*HALO &&
                      col >= 2*HALO && col < RC-2*HALO);
                if (ring) {   // ring cells always in-domain
                    const size_t g = (size_t)b*NZX + (size_t)(oz+i)*NX + gx;
                    __hip_atomic_store(&Gp[g], cur[m],
                                       __ATOMIC_RELAXED, __HIP_MEMORY_SCOPE_AGENT);
                }
            }
        }

        if ((t & 7) == 7) {
            const int o = t >> 3;
            const bool exch = (t < NT-1);
            float* Gc = ws + (size_t)(o & 1) * 2*BNZX;   // ping-pong frames
            float* Gp = Gc + BNZX;
            if (exch) {
                // cur-frame ring store (prv-half already issued at s=6)
                #pragma unroll
                for (int m = 0; m < 5; ++m) {
                    const int i = r0w + m;
                    const bool ring =
                        (i >= HALO && i < RR-HALO && col >= HALO && col < RC-HALO)
                     && !(i >= 2*HALO && i < RR-2*HALO &&
                          col >= 2*HALO && col < RC-2*HALO);
                    if (ring) {
                        const size_t g = (size_t)b*NZX + (size_t)(oz+i)*NX + gx;
                        __hip_atomic_store(&Gc[g], cur[m],
                                           __ATOMIC_RELAXED, __HIP_MEMORY_SCOPE_AGENT);
                    }
                }
            }
            __syncthreads();   // recBuf visible; ALL ring stores drained (vmcnt0)
            if (exch && tid == 0)
                __hip_atomic_store(&flags[blk * FSTRIDE], (unsigned)(o + 1),
                                   __ATOMIC_RELAXED, __HIP_MEMORY_SCOPE_AGENT);
            // receiver flush overlaps the neighbor wait
            for (int k = tid; k < recCnt*8; k += NTHR) {
                int p = k >> 3, s2 = k & 7;
                y[(size_t)((o<<3)+s2)*(BB*NREC) + recOut[p]] = recBuf[p][s2];
            }
            if (exch) {
                const unsigned gen = (unsigned)(o + 1);
                if (tid < 64) {
                    for (;;) {
                        unsigned f = __hip_atomic_load(&flags[nbId * FSTRIDE],
                                         __ATOMIC_RELAXED, __HIP_MEMORY_SCOPE_AGENT);
                        if (__all(f >= gen)) break;
                        __builtin_amdgcn_s_sleep(1);
                    }
                }
                __syncthreads();
                const bool colH = (col < HALO || col >= RC-HALO);
                const bool gxIn = (gx >= 0 && gx < NX);
                #pragma unroll
                for (int m = 0; m < 5; ++m) {
                    const int i = r0w + m;
                    if (colH || i < HALO || i >= RR-HALO) {
                        const int gz = oz + i;
                        if (gxIn && gz >= 0 && gz < NZ) {   // BOTH bounds (r2 lesson)
                            const size_t g = (size_t)b*NZX + (size_t)gz*NX + gx;
                            cur[m] = __hip_atomic_load(&Gc[g],
                                         __ATOMIC_RELAXED, __HIP_MEMORY_SCOPE_AGENT);
                            prv[m] = __hip_atomic_load(&Gp[g],
                                         __ATOMIC_RELAXED, __HIP_MEMORY_SCOPE_AGENT);
                        } else { cur[m] = 0.f; prv[m] = 0.f; }
                    }
                }
                bnd[pw][2*w  ][col] = cur[0];
                bnd[pw][2*w+1][col] = cur[4];
            }
        }
        __syncthreads();
    }
}

extern "C" void kernel_launch(void* const* d_in, const int* in_sizes, int n_in,
                              void* d_out, int out_size, void* d_ws, size_t ws_size,
                              hipStream_t stream) {
    const float* x     = (const float*)d_in[0];
    const float* vp    = (const float*)d_in[1];
    const int*   src_y = (const int*)d_in[2];
    const int*   src_x = (const int*)d_in[3];
    const int*   rec_y = (const int*)d_in[4];
    const int*   rec_x = (const int*)d_in[5];
    float* y  = (float*)d_out;
    float* ws = (float*)d_ws;   // 4*BNZX frame floats + 512*16 flag words

    wave_init<<<(NBLK*FSTRIDE + 255)/256, 256, 0, stream>>>((unsigned*)(ws + 4*BNZX));
    // DYN_LDS bytes of (unused) dynamic LDS pad the group segment to ~54.3KB:
    // hardware can then host at most 2 blocks/CU -> exactly 2 everywhere.
    wave_tiled<<<NBLK, NTHR, DYN_LDS, stream>>>(ws, vp, x, src_y, src_x,
                                                rec_y, rec_x, y);
}

// Round 12
// 267.255 us; speedup vs baseline: 1.1499x; 1.0188x over previous
//
#include <hip/hip_runtime.h>

#define BB 4
#define NT 256
#define NZ 384
#define NX 384
#define NREC 128
#define NZX (NZ*NX)        // 147456
#define BNZX (BB*NZX)      // 589824
#define DT 0.001f
#define INV_DH2 0.01f      // 1/(10*10)

#define TR 24              // owned tile rows
#define TC 48              // owned tile cols
#define HALO 8
#define RR 40              // region rows = 8 waves x 5
#define RC 64              // region cols = 64 lanes
#define NTDR 16            // 384/24
#define NTDC 8             // 384/48
#define NBLK 512           // 4 batches x 128 tiles -> exactly 2 blocks/CU
#define NTHR 512           // 8 waves: wave w owns rows 5w..5w+4, lane = col
#define FLAGW 16           // words per block: 8 wave-flags x 2, one 64B line
#define DYN_LDS 40960      // pad LDS to ~54.3KB: HW caps residency at 2/CU,
                           // 512 blocks / 256 CUs -> EXACTLY 2 each (pigeonhole)

__global__ void wave_init(unsigned* flags) {
    int i = blockIdx.x * blockDim.x + threadIdx.x;
    if (i < NBLK * FLAGW) flags[i] = 0u;
}

__device__ inline float dpp_shl1(float v) {
    return __int_as_float(__builtin_amdgcn_update_dpp(
        0, __float_as_int(v), 0x130 /*WAVE_SHL1*/, 0xf, 0xf, true));
}
__device__ inline float dpp_shr1(float v) {
    return __int_as_float(__builtin_amdgcn_update_dpp(
        0, __float_as_int(v), 0x138 /*WAVE_SHR1*/, 0xf, 0xf, true));
}

__global__ __launch_bounds__(NTHR)
void wave_tiled(float* __restrict__ ws, const float* __restrict__ vp,
                const float* __restrict__ x,
                const int* __restrict__ src_y, const int* __restrict__ src_x,
                const int* __restrict__ rec_y, const int* __restrict__ rec_x,
                float* __restrict__ y) {
    __shared__ float bnd[2][16][RC];     // [parity][2*wave+{top,bot}][col]
    __shared__ float recBuf[NREC][8];    // receiver samples, flushed per window
    __shared__ float xs[NT];             // this batch's source trace
    __shared__ int recLoc[NREC], recOut[NREC];
    __shared__ int recCnt;

    unsigned* flags = (unsigned*)(ws + 4*BNZX);

    const int tid = threadIdx.x;
    const int col = tid & 63;
    const int w   = tid >> 6;
    const int r0w = w * 5;
    const int blk = blockIdx.x;
    const int b   = blk >> 7;            // 0..3
    const int rem = blk & 127;
    const int tz  = rem >> 3;            // 0..15
    const int tx  = rem & 7;             // 0..7
    const int oz  = tz*TR - HALO, ox = tx*TC - HALO;
    const int gx  = ox + col;
    const int sy = src_y[b], sx = src_x[b];

    if (tid == 0) recCnt = 0;
    for (int k = tid; k < 2*16*RC; k += NTHR) ((float*)bnd)[k] = 0.f;
    for (int k = tid; k < NT; k += NTHR) xs[k] = x[b*NT + k];
    __syncthreads();
    for (int r = tid; r < NREC; r += NTHR) {
        int ry = rec_y[r], rx = rec_x[r];
        if (ry/TR == tz && rx/TC == tx) {
            int p = atomicAdd(&recCnt, 1);
            recLoc[p] = ((ry - oz) << 6) | (rx - ox);
            recOut[p] = b*NREC + r;
        }
    }
    __syncthreads();

    // per-thread receiver ownership cache (cap 4, LDS-loop fallback)
    int myN = 0, myM[4], myP[4];
    bool ovf = false;
    for (int p = 0; p < recCnt; ++p) {
        int rl = recLoc[p];
        if ((rl & 63) == col) {
            int rm = (rl >> 6) - r0w;
            if ((unsigned)rm < 5u) {
                if (myN < 4) { myM[myN] = rm; myP[myN] = p; ++myN; }
                else ovf = true;
            }
        }
    }

    // per-lane poll target for wave 0: lane l polls neighbor (l>>3)'s
    // wave-(l&7) flag. 64 lanes cover 8 neighbors x 8 waves. Out-of-domain
    // neighbors (and unused lanes) default to OWN block's wave flag, which is
    // posted before the poll -> self-satisfied.
    int nbF = blk * FLAGW + 2*(tid & 7);
    if (tid < 64) {
        int n = tid >> 3;                    // 0..7
        int d = n + (n >= 4);                // 0..8 skipping center 4
        int nz2 = tz + d/3 - 1, nx2 = tx + d%3 - 1;
        if ((unsigned)nz2 < (unsigned)NTDR && (unsigned)nx2 < (unsigned)NTDC)
            nbF = (((b << 7) | (nz2 << 3) | nx2) * FLAGW) + 2*(tid & 7);
    }

    // per-thread column state: 5 rows in registers
    float cur[5], prv[5], c2i[5];
    #pragma unroll
    for (int m = 0; m < 5; ++m) {
        cur[m] = 0.f; prv[m] = 0.f;
        const int gz = oz + r0w + m;
        const bool inner = (gz > 0 && gz < NZ-1 && gx > 0 && gx < NX-1);
        const float v = inner ? vp[gz*NX + gx] * DT : 0.f;
        c2i[m] = v * v * INV_DH2;    // 0 at edges -> lap auto-masked
    }
    const bool srcCol = (gx == sx);
    const int  srcM   = sy - oz - r0w;
    const int  iuUp   = (2*w-1 < 0) ? 0 : 2*w-1;
    const int  iuDn   = (2*w+2 > 15) ? 15 : 2*w+2;
    __syncthreads();

    #pragma unroll 1
    for (int t = 0; t < NT; ++t) {
        const int pr = t & 1, pw = pr ^ 1;
        const float upB = bnd[pr][iuUp][col];
        const float dnB = bnd[pr][iuDn][col];

        float hn[5];
        #pragma unroll
        for (int m = 0; m < 5; ++m) {
            const float ce = cur[m];
            const float up = (m == 0) ? upB : cur[m-1];
            const float dn = (m == 4) ? dnB : cur[m+1];
            const float lf = dpp_shl1(ce);
            const float rt = dpp_shr1(ce);
            const float s  = (up + dn) + (lf + rt);
            hn[m] = fmaf(2.f, ce, -prv[m]) + c2i[m] * fmaf(-4.f, ce, s);
        }
        #pragma unroll
        for (int m = 0; m < 5; ++m) { prv[m] = cur[m]; cur[m] = hn[m]; }

        if (srcCol && (unsigned)srcM < 5u) {
            const float xv = xs[t];
            #pragma unroll
            for (int m = 0; m < 5; ++m) if (m == srcM) cur[m] += xv;
        }
        // receiver sampling -> LDS buffer (no global ops in the step loop)
        {
            const int s2 = t & 7;
            if (ovf) {
                for (int p = 0; p < recCnt; ++p) {
                    int rl = recLoc[p];
                    if ((rl & 63) == col) {
                        int rm = (rl >> 6) - r0w;
                        if ((unsigned)rm < 5u) {
                            float v = cur[0];
                            #pragma unroll
                            for (int m = 1; m < 5; ++m) if (rm == m) v = cur[m];
                            recBuf[p][s2] = v;
                        }
                    }
                }
            } else {
                #pragma unroll
                for (int k = 0; k < 4; ++k) {
                    if (k < myN) {
                        float v = cur[0];
                        #pragma unroll
                        for (int m = 1; m < 5; ++m) if (myM[k] == m) v = cur[m];
                        recBuf[myP[k]][s2] = v;
                    }
                }
            }
        }
        bnd[pw][2*w  ][col] = cur[0];
        bnd[pw][2*w+1][col] = cur[4];

        if ((t & 7) == 7) {
            const int o = t >> 3;
            const bool exch = (t < NT-1);
            float* Gc = ws + (size_t)(o & 1) * 2*BNZX;   // ping-pong frames
            float* Gp = Gc + BNZX;
            if (exch) {
                // ring: depth [HALO,2*HALO) band of the owned region
                #pragma unroll
                for (int m = 0; m < 5; ++m) {
                    const int i = r0w + m;
                    const bool ring =
                        (i >= HALO && i < RR-HALO && col >= HALO && col < RC-HALO)
                     && !(i >= 2*HALO && i < RR-2*HALO &&
                          col >= 2*HALO && col < RC-2*HALO);
                    if (ring) {   // ring cells always in-domain
                        const size_t g = (size_t)b*NZX + (size_t)(oz+i)*NX + gx;
                        __hip_atomic_store(&Gc[g], cur[m],
                                           __ATOMIC_RELAXED, __HIP_MEMORY_SCOPE_AGENT);
                        __hip_atomic_store(&Gp[g], prv[m],
                                           __ATOMIC_RELAXED, __HIP_MEMORY_SCOPE_AGENT);
                    }
                }
                // per-wave drain + per-wave flag post: vmcnt is a per-wave
                // counter, so each wave posts as soon as ITS stores reach the
                // coherence point -- no block barrier, no slowest-wave wait.
                asm volatile("s_waitcnt vmcnt(0)" ::: "memory");
                if ((tid & 63) == 0)
                    __hip_atomic_store(&flags[blk * FLAGW + 2*w], (unsigned)(o + 1),
                                       __ATOMIC_RELAXED, __HIP_MEMORY_SCOPE_AGENT);
            }
            __syncthreads();   // recBuf writes of this window visible
            // receiver flush overlaps the neighbor wait
            for (int k = tid; k < recCnt*8; k += NTHR) {
                int p = k >> 3, s2 = k & 7;
                y[(size_t)((o<<3)+s2)*(BB*NREC) + recOut[p]] = recBuf[p][s2];
            }
            if (exch) {
                const unsigned gen = (unsigned)(o + 1);
                if (tid < 64) {   // 64-lane poll: 8 neighbors x 8 wave-flags
                    for (;;) {
                        unsigned f = __hip_atomic_load(&flags[nbF],
                                         __ATOMIC_RELAXED, __HIP_MEMORY_SCOPE_AGENT);
                        if (__all(f >= gen)) break;
                        __builtin_amdgcn_s_sleep(1);
                    }
                }
                __syncthreads();
                const bool colH = (col < HALO || col >= RC-HALO);
                const bool gxIn = (gx >= 0 && gx < NX);
                #pragma unroll
                for (int m = 0; m < 5; ++m) {
                    const int i = r0w + m;
                    if (colH || i < HALO || i >= RR-HALO) {
                        const int gz = oz + i;
                        if (gxIn && gz >= 0 && gz < NZ) {   // BOTH bounds (r2 lesson)
                            const size_t g = (size_t)b*NZX + (size_t)gz*NX + gx;
                            cur[m] = __hip_atomic_load(&Gc[g],
                                         __ATOMIC_RELAXED, __HIP_MEMORY_SCOPE_AGENT);
                            prv[m] = __hip_atomic_load(&Gp[g],
                                         __ATOMIC_RELAXED, __HIP_MEMORY_SCOPE_AGENT);
                        } else { cur[m] = 0.f; prv[m] = 0.f; }
                    }
                }
                bnd[pw][2*w  ][col] = cur[0];
                bnd[pw][2*w+1][col] = cur[4];
            }
        }
        __syncthreads();
    }
}

extern "C" void kernel_launch(void* const* d_in, const int* in_sizes, int n_in,
                              void* d_out, int out_size, void* d_ws, size_t ws_size,
                              hipStream_t stream) {
    const float* x     = (const float*)d_in[0];
    const float* vp    = (const float*)d_in[1];
    const int*   src_y = (const int*)d_in[2];
    const int*   src_x = (const int*)d_in[3];
    const int*   rec_y = (const int*)d_in[4];
    const int*   rec_x = (const int*)d_in[5];
    float* y  = (float*)d_out;
    float* ws = (float*)d_ws;   // 4*BNZX frame floats + 512*16 flag words

    wave_init<<<(NBLK*FLAGW + 255)/256, 256, 0, stream>>>((unsigned*)(ws + 4*BNZX));
    // DYN_LDS bytes of (unused) dynamic LDS pad the group segment to ~54.3KB:
    // hardware can then host at most 2 blocks/CU -> exactly 2 everywhere.
    wave_tiled<<<NBLK, NTHR, DYN_LDS, stream>>>(ws, vp, x, src_y, src_x,
                                                rec_y, rec_x, y);
}

// Round 13
// 247.447 us; speedup vs baseline: 1.2420x; 1.0800x over previous
//
#include <hip/hip_runtime.h>

#define BB 4
#define NT 256
#define NZ 384
#define NX 384
#define NREC 128
#define NZX (NZ*NX)        // 147456
#define BNZX (BB*NZX)      // 589824
#define DT 0.001f
#define INV_DH2 0.01f      // 1/(10*10)

#define TR 24              // owned tile rows
#define TC 48              // owned tile cols
#define HALO 8
#define RR 40              // region rows = 8 waves x 5
#define RC 64              // region cols = 64 lanes
#define NTDR 16            // 384/24
#define NTDC 8             // 384/48
#define NBLK 512           // 4 batches x 128 tiles -> exactly 2 blocks/CU
#define NTHR 512           // 8 waves: wave w owns rows 5w..5w+4, lane = col
#define FSTRIDE 16         // flag spread (64 B)
#define DYN_LDS 40960      // pad LDS to ~54.3KB: HW caps residency at 2/CU,
                           // 512 blocks / 256 CUs -> EXACTLY 2 each (pigeonhole)

__global__ void wave_init(unsigned* flags) {
    int i = blockIdx.x * blockDim.x + threadIdx.x;
    if (i < NBLK * FSTRIDE) flags[i] = 0u;
}

__device__ inline float dpp_shl1(float v) {
    return __int_as_float(__builtin_amdgcn_update_dpp(
        0, __float_as_int(v), 0x130 /*WAVE_SHL1*/, 0xf, 0xf, true));
}
__device__ inline float dpp_shr1(float v) {
    return __int_as_float(__builtin_amdgcn_update_dpp(
        0, __float_as_int(v), 0x138 /*WAVE_SHR1*/, 0xf, 0xf, true));
}

// r8 structure (best measured: 193 us kernel-time, twice reproduced).
// Dynamic overlap: exactly 2 blocks/CU (LDS-pad pigeonhole); while one
// block's wave0 polls (s_sleep yields the SIMD) and its other waves sit in
// s_barrier, the co-resident block computes. Exchange mechanics r0-verbatim:
// scalar 4B relaxed-agent sc1 accesses (every variant tried - 8B packing,
// bulk release/acquire fences, dwordx4 asm, split stores, per-wave flags -
// measured slower; see session ledger r3-r12).
__device__ inline void grid_sync(unsigned* flags, unsigned gen, int nbId) {
    __syncthreads();   // drains vmcnt(0): ring stores at LLC before flag store
    if (threadIdx.x < 64) {
        if (threadIdx.x == 0)
            __hip_atomic_store(&flags[blockIdx.x * FSTRIDE], gen,
                               __ATOMIC_RELAXED, __HIP_MEMORY_SCOPE_AGENT);
        for (;;) {
            unsigned f = __hip_atomic_load(&flags[nbId * FSTRIDE],
                             __ATOMIC_RELAXED, __HIP_MEMORY_SCOPE_AGENT);
            if (__all(f >= gen)) break;
            __builtin_amdgcn_s_sleep(1);
        }
    }
    __syncthreads();
}

__global__ __launch_bounds__(NTHR)
void wave_tiled(float* __restrict__ ws, const float* __restrict__ vp,
                const float* __restrict__ x,
                const int* __restrict__ src_y, const int* __restrict__ src_x,
                const int* __restrict__ rec_y, const int* __restrict__ rec_x,
                float* __restrict__ y) {
    __shared__ float bnd[2][16][RC];     // [parity][2*wave+{top,bot}][col]
    __shared__ float recBuf[NREC][8];    // receiver samples, flushed per window
    __shared__ float xs[NT];             // this batch's source trace
    __shared__ int recLoc[NREC], recOut[NREC];
    __shared__ int recCnt;

    unsigned* flags = (unsigned*)(ws + 4*BNZX);

    const int tid = threadIdx.x;
    const int col = tid & 63;
    const int w   = tid >> 6;
    const int r0w = w * 5;
    const int blk = blockIdx.x;
    const int b   = blk >> 7;            // 0..3
    const int rem = blk & 127;
    const int tz  = rem >> 3;            // 0..15
    const int tx  = rem & 7;             // 0..7
    const int oz  = tz*TR - HALO, ox = tx*TC - HALO;
    const int gx  = ox + col;
    const int sy = src_y[b], sx = src_x[b];

    if (tid == 0) recCnt = 0;
    for (int k = tid; k < 2*16*RC; k += NTHR) ((float*)bnd)[k] = 0.f;
    for (int k = tid; k < NT; k += NTHR) xs[k] = x[b*NT + k];
    __syncthreads();
    for (int r = tid; r < NREC; r += NTHR) {
        int ry = rec_y[r], rx = rec_x[r];
        if (ry/TR == tz && rx/TC == tx) {
            int p = atomicAdd(&recCnt, 1);
            recLoc[p] = ((ry - oz) << 6) | (rx - ox);
            recOut[p] = b*NREC + r;
        }
    }
    __syncthreads();

    // per-thread receiver ownership cache (cap 4, LDS-loop fallback)
    int myN = 0, myM[4], myP[4];
    bool ovf = false;
    for (int p = 0; p < recCnt; ++p) {
        int rl = recLoc[p];
        if ((rl & 63) == col) {
            int rm = (rl >> 6) - r0w;
            if ((unsigned)rm < 5u) {
                if (myN < 4) { myM[myN] = rm; myP[myN] = p; ++myN; }
                else ovf = true;
            }
        }
    }

    // neighbor ids for the sync (lanes 0..7 of wave 0; others self)
    int nbId = blk;
    if (tid < 8) {
        int d = tid + (tid >= 4);            // 0..8 skipping center 4
        int nz2 = tz + d/3 - 1, nx2 = tx + d%3 - 1;
        if ((unsigned)nz2 < (unsigned)NTDR && (unsigned)nx2 < (unsigned)NTDC)
            nbId = (b << 7) | (nz2 << 3) | nx2;
    }

    // per-thread column state: 5 rows in registers
    float cur[5], prv[5], c2i[5];
    #pragma unroll
    for (int m = 0; m < 5; ++m) {
        cur[m] = 0.f; prv[m] = 0.f;
        const int gz = oz + r0w + m;
        const bool inner = (gz > 0 && gz < NZ-1 && gx > 0 && gx < NX-1);
        const float v = inner ? vp[gz*NX + gx] * DT : 0.f;
        c2i[m] = v * v * INV_DH2;    // 0 at edges -> lap auto-masked
    }
    const bool srcCol = (gx == sx);
    const int  srcM   = sy - oz - r0w;
    const int  iuUp   = (2*w-1 < 0) ? 0 : 2*w-1;
    const int  iuDn   = (2*w+2 > 15) ? 15 : 2*w+2;
    __syncthreads();

    #pragma unroll 1
    for (int t = 0; t < NT; ++t) {
        const int pr = t & 1, pw = pr ^ 1;
        const float upB = bnd[pr][iuUp][col];
        const float dnB = bnd[pr][iuDn][col];

        float hn[5];
        #pragma unroll
        for (int m = 0; m < 5; ++m) {
            const float ce = cur[m];
            const float up = (m == 0) ? upB : cur[m-1];
            const float dn = (m == 4) ? dnB : cur[m+1];
            const float lf = dpp_shl1(ce);
            const float rt = dpp_shr1(ce);
            const float s  = (up + dn) + (lf + rt);
            hn[m] = fmaf(2.f, ce, -prv[m]) + c2i[m] * fmaf(-4.f, ce, s);
        }
        #pragma unroll
        for (int m = 0; m < 5; ++m) { prv[m] = cur[m]; cur[m] = hn[m]; }

        if (srcCol && (unsigned)srcM < 5u) {
            const float xv = xs[t];
            #pragma unroll
            for (int m = 0; m < 5; ++m) if (m == srcM) cur[m] += xv;
        }
        // receiver sampling -> LDS buffer (no global ops in the step loop)
        {
            const int s2 = t & 7;
            if (ovf) {
                for (int p = 0; p < recCnt; ++p) {
                    int rl = recLoc[p];
                    if ((rl & 63) == col) {
                        int rm = (rl >> 6) - r0w;
                        if ((unsigned)rm < 5u) {
                            float v = cur[0];
                            #pragma unroll
                            for (int m = 1; m < 5; ++m) if (rm == m) v = cur[m];
                            recBuf[p][s2] = v;
                        }
                    }
                }
            } else {
                #pragma unroll
                for (int k = 0; k < 4; ++k) {
                    if (k < myN) {
                        float v = cur[0];
                        #pragma unroll
                        for (int m = 1; m < 5; ++m) if (myM[k] == m) v = cur[m];
                        recBuf[myP[k]][s2] = v;
                    }
                }
            }
        }
        bnd[pw][2*w  ][col] = cur[0];
        bnd[pw][2*w+1][col] = cur[4];

        if ((t & 7) == 7) {
            const int o = t >> 3;
            const bool exch = (t < NT-1);
            float* Gc = ws + (size_t)(o & 1) * 2*BNZX;   // ping-pong frames
            float* Gp = Gc + BNZX;
            if (exch) {
                // ring: depth [HALO,2*HALO) band of the owned region
                #pragma unroll
                for (int m = 0; m < 5; ++m) {
                    const int i = r0w + m;
                    const bool ring =
                        (i >= HALO && i < RR-HALO && col >= HALO && col < RC-HALO)
                     && !(i >= 2*HALO && i < RR-2*HALO &&
                          col >= 2*HALO && col < RC-2*HALO);
                    if (ring) {   // ring cells always in-domain
                        const size_t g = (size_t)b*NZX + (size_t)(oz+i)*NX + gx;
                        __hip_atomic_store(&Gc[g], cur[m],
                                           __ATOMIC_RELAXED, __HIP_MEMORY_SCOPE_AGENT);
                        __hip_atomic_store(&Gp[g], prv[m],
                                           __ATOMIC_RELAXED, __HIP_MEMORY_SCOPE_AGENT);
                    }
                }
            }
            __syncthreads();   // recBuf visible; ring stores drained (vmcnt0)
            if (exch && tid == 0)
                __hip_atomic_store(&flags[blk * FSTRIDE], (unsigned)(o + 1),
                                   __ATOMIC_RELAXED, __HIP_MEMORY_SCOPE_AGENT);
            // receiver flush overlaps the neighbor wait
            for (int k = tid; k < recCnt*8; k += NTHR) {
                int p = k >> 3, s2 = k & 7;
                y[(size_t)((o<<3)+s2)*(BB*NREC) + recOut[p]] = recBuf[p][s2];
            }
            if (exch) {
                const unsigned gen = (unsigned)(o + 1);
                if (tid < 64) {
                    for (;;) {
                        unsigned f = __hip_atomic_load(&flags[nbId * FSTRIDE],
                                         __ATOMIC_RELAXED, __HIP_MEMORY_SCOPE_AGENT);
                        if (__all(f >= gen)) break;
                        __builtin_amdgcn_s_sleep(1);
                    }
                }
                __syncthreads();
                const bool colH = (col < HALO || col >= RC-HALO);
                const bool gxIn = (gx >= 0 && gx < NX);
                #pragma unroll
                for (int m = 0; m < 5; ++m) {
                    const int i = r0w + m;
                    if (colH || i < HALO || i >= RR-HALO) {
                        const int gz = oz + i;
                        if (gxIn && gz >= 0 && gz < NZ) {   // BOTH bounds (r2 lesson)
                            const size_t g = (size_t)b*NZX + (size_t)gz*NX + gx;
                            cur[m] = __hip_atomic_load(&Gc[g],
                                         __ATOMIC_RELAXED, __HIP_MEMORY_SCOPE_AGENT);
                            prv[m] = __hip_atomic_load(&Gp[g],
                                         __ATOMIC_RELAXED, __HIP_MEMORY_SCOPE_AGENT);
                        } else { cur[m] = 0.f; prv[m] = 0.f; }
                    }
                }
                bnd[pw][2*w  ][col] = cur[0];
                bnd[pw][2*w+1][col] = cur[4];
            }
        }
        __syncthreads();
    }
}

extern "C" void kernel_launch(void* const* d_in, const int* in_sizes, int n_in,
                              void* d_out, int out_size, void* d_ws, size_t ws_size,
                              hipStream_t stream) {
    const float* x     = (const float*)d_in[0];
    const float* vp    = (const float*)d_in[1];
    const int*   src_y = (const int*)d_in[2];
    const int*   src_x = (const int*)d_in[3];
    const int*   rec_y = (const int*)d_in[4];
    const int*   rec_x = (const int*)d_in[5];
    float* y  = (float*)d_out;
    float* ws = (float*)d_ws;   // 4*BNZX frame floats + 512*16 flag words

    wave_init<<<(NBLK*FSTRIDE + 255)/256, 256, 0, stream>>>((unsigned*)(ws + 4*BNZX));
    // DYN_LDS bytes of (unused) dynamic LDS pad the group segment to ~54.3KB:
    // hardware can then host at most 2 blocks/CU -> exactly 2 everywhere.
    wave_tiled<<<NBLK, NTHR, DYN_LDS, stream>>>(ws, vp, x, src_y, src_x,
                                                rec_y, rec_x, y);
}